// Round 4
// baseline (3554.228 us; speedup 1.0000x reference)
//
#include <hip/hip_runtime.h>

#define H 128
#define KV 256

__device__ __forceinline__ float bf2f(unsigned short u) {
  return __uint_as_float(((unsigned)u) << 16);
}
__device__ __forceinline__ unsigned short f2bf(float f) {
  unsigned b = __float_as_uint(f);
  b += 0x7FFFu + ((b >> 16) & 1u);   // round-to-nearest-even
  return (unsigned short)(b >> 16);
}
// order-preserving float<->uint for atomicMax-based segment max
__device__ __forceinline__ unsigned f2s(float f) {
  unsigned b = __float_as_uint(f);
  return (b & 0x80000000u) ? ~b : (b | 0x80000000u);
}
__device__ __forceinline__ float s2f(unsigned u) {
  unsigned b = (u & 0x80000000u) ? (u ^ 0x80000000u) : ~u;
  return __uint_as_float(b);
}

// kvn storage: fp32 (KB=false) or bf16 (KB=true) depending on ws_size tier
template<bool KB>
__device__ __forceinline__ float kv_load(const void* kvn, int idx) {
  if (KB) return bf2f(((const unsigned short*)kvn)[idx]);
  else    return ((const float*)kvn)[idx];
}
template<bool KB>
__device__ __forceinline__ void kv_store(void* kvn, int idx, float v) {
  if (KB) ((unsigned short*)kvn)[idx] = f2bf(v);
  else    ((float*)kvn)[idx] = v;
}

__global__ __launch_bounds__(256) void k_zero(float* __restrict__ p, int n) {
  int i = blockIdx.x * 256 + threadIdx.x;
  if (i < n) p[i] = 0.f;
}

// diagnostic: ws_size too small for any tier
__global__ __launch_bounds__(256) void k_sentinel(float* __restrict__ out, int n) {
  int i = blockIdx.x * 256 + threadIdx.x;
  if (i < n) out[i] = 1000.0f;
}

// K1: qn = h@Wq + bq (N x 128), kvn = h@Wkv[9:,:] + bkv (N x 256); 4 nodes/block
template<bool KB>
__global__ __launch_bounds__(384) void k_node_proj(
    const float* __restrict__ h, const float* __restrict__ Wq,
    const float* __restrict__ bq, const float* __restrict__ Wkv,
    const float* __restrict__ bkv, float* __restrict__ qn,
    void* __restrict__ kvn, int N)
{
  __shared__ float hs[4][H];
  const int n0 = blockIdx.x * 4;
  const int t = threadIdx.x;
  for (int idx = t; idx < 4*H; idx += 384) {
    int nn = idx >> 7, jj = idx & 127;
    hs[nn][jj] = (n0 + nn < N) ? h[(size_t)(n0+nn)*H + jj] : 0.f;
  }
  __syncthreads();
  float a0 = 0.f, a1 = 0.f, a2 = 0.f, a3 = 0.f;
  if (t < H) {
    #pragma unroll 4
    for (int j = 0; j < H; ++j) {
      float w = Wq[j*H + t];
      a0 += hs[0][j]*w; a1 += hs[1][j]*w; a2 += hs[2][j]*w; a3 += hs[3][j]*w;
    }
    float b = bq[t];
    if (n0+0 < N) qn[(size_t)(n0+0)*H + t] = a0 + b;
    if (n0+1 < N) qn[(size_t)(n0+1)*H + t] = a1 + b;
    if (n0+2 < N) qn[(size_t)(n0+2)*H + t] = a2 + b;
    if (n0+3 < N) qn[(size_t)(n0+3)*H + t] = a3 + b;
  } else {
    int c = t - H;
    #pragma unroll 4
    for (int j = 0; j < H; ++j) {
      float w = Wkv[(9 + j)*KV + c];
      a0 += hs[0][j]*w; a1 += hs[1][j]*w; a2 += hs[2][j]*w; a3 += hs[3][j]*w;
    }
    float b = bkv[c];
    if (n0+0 < N) kv_store<KB>(kvn, (n0+0)*KV + c, a0 + b);
    if (n0+1 < N) kv_store<KB>(kvn, (n0+1)*KV + c, a1 + b);
    if (n0+2 < N) kv_store<KB>(kvn, (n0+2)*KV + c, a2 + b);
    if (n0+3 < N) kv_store<KB>(kvn, (n0+3)*KV + c, a3 + b);
  }
}

// K2: per-edge alpha_raw = q . k (wave per edge), segment max via sortable atomicMax
template<bool KB>
__global__ __launch_bounds__(256) void k_edge_alpha(
    const float* __restrict__ coord, const int* __restrict__ row,
    const int* __restrict__ col, const float* __restrict__ Wkv,
    const float* __restrict__ qn, const void* __restrict__ kvn,
    float* __restrict__ alpha_ws, unsigned* __restrict__ segmax, int E)
{
  int lane = threadIdx.x & 63;
  int gw = (blockIdx.x * blockDim.x + threadIdx.x) >> 6;
  int nw = (gridDim.x * blockDim.x) >> 6;
  for (int e = gw; e < E; e += nw) {
    int r = row[e], c = col[e];
    float cd[9], radial[9];
    const float* cr = coord + (size_t)r*9;
    const float* cc = coord + (size_t)c*9;
    #pragma unroll
    for (int i = 0; i < 9; ++i) cd[i] = cr[i] - cc[i];
    #pragma unroll
    for (int a = 0; a < 3; ++a)
      #pragma unroll
      for (int b = 0; b < 3; ++b)
        radial[a*3+b] = cd[a*3]*cd[b*3] + cd[a*3+1]*cd[b*3+1] + cd[a*3+2]*cd[b*3+2];
    const float* q = qn + (size_t)r*H;
    float acc = 0.f;
    #pragma unroll
    for (int t = 0; t < 2; ++t) {
      int j = lane + 64*t;
      float kj = kv_load<KB>(kvn, c*KV + 2*j);   // bkv already folded into kvn
      #pragma unroll
      for (int p = 0; p < 9; ++p) kj += radial[p] * Wkv[p*KV + 2*j];
      acc += q[j] * kj;
    }
    #pragma unroll
    for (int m = 32; m > 0; m >>= 1) acc += __shfl_xor(acc, m, 64);
    if (lane == 0) {
      alpha_ws[e] = acc;
      atomicMax(&segmax[r], f2s(acc));
    }
  }
}

// K3: ex = exp(min(alpha - segmax[row], 0)); segsum += ex.
// min(.,0) is identity when segmax holds the true max, and bounds ex<=1 so
// segsum >= 1 for every row with edges => alpha_n in [0,1], never NaN/inf.
__global__ __launch_bounds__(256) void k_softmax_exp(
    const int* __restrict__ row, const unsigned* __restrict__ segmax,
    float* __restrict__ alpha_ws, float* __restrict__ segsum, int E)
{
  int e = blockIdx.x * 256 + threadIdx.x;
  if (e >= E) return;
  int r = row[e];
  float d = alpha_ws[e] - s2f(segmax[r]);
  float ex = __expf(fminf(d, 0.f));
  alpha_ws[e] = ex;
  atomicAdd(&segsum[r], ex);
}

// K4: main per-edge kernel. blockIdx%4 selects an o-quarter of Wc1 (bf16x2 in LDS).
// Each quarter-flavor processes ALL edges; coord_v partials combine via cagg atomics.
// Quarter q owns agg atomics for j in [32q,32q+32); quarter 0 writes alpha out.
template<bool KB>
__global__ __launch_bounds__(256) void k_edge_main(
    const float* __restrict__ coord, const int* __restrict__ row,
    const int* __restrict__ col, const float* __restrict__ Wkv,
    const float* __restrict__ Wc1, const float* __restrict__ Wc2,
    const void* __restrict__ kvn, const float* __restrict__ alpha_ws,
    const float* __restrict__ segsum, float* __restrict__ agg,
    float* __restrict__ cagg, float* __restrict__ alpha_out, int E)
{
  __shared__ unsigned w2[64*128];   // 32KB: (Wc1[2j][o], Wc1[2j+1][o]) packed bf16x2
  __shared__ float wc2q[128*3];
  __shared__ float vsh[4][128];
  const int quarter = blockIdx.x & 3;
  const int obase = quarter << 7;
  const int tid = threadIdx.x;
  const float* Wc1q = Wc1 + obase;
  for (int idx = tid; idx < 64*128; idx += 256) {
    int j2 = idx >> 7, o = idx & 127;
    unsigned lo = f2bf(Wc1q[(2*j2)*512 + o]);
    unsigned hi = f2bf(Wc1q[(2*j2+1)*512 + o]);
    w2[idx] = lo | (hi << 16);
  }
  for (int idx = tid; idx < 128*3; idx += 256)
    wc2q[idx] = Wc2[obase*3 + idx];
  __syncthreads();

  const int wid = tid >> 6, lane = tid & 63;
  const int gw = (blockIdx.x >> 2)*4 + wid;   // wave id within quarter
  const int nw = gridDim.x;                   // (gridDim/4 blocks)*4 waves per quarter
  const int iters = (E + nw - 1)/nw;
  float* vw = vsh[wid];
  const float2* vw2 = (const float2*)vw;
  for (int it = 0; it < iters; ++it) {
    int e = gw + it*nw;
    bool active = e < E;                      // wave-uniform
    int r = 0;
    float alpha_n = 0.f, cd[9];
    if (active) {
      r = row[e];
      int c = col[e];
      alpha_n = alpha_ws[e] / fmaxf(segsum[r], 1e-30f);
      const float* crd = coord + (size_t)r*9;
      const float* ccd = coord + (size_t)c*9;
      float radial[9];
      #pragma unroll
      for (int i = 0; i < 9; ++i) cd[i] = crd[i] - ccd[i];
      #pragma unroll
      for (int a = 0; a < 3; ++a)
        #pragma unroll
        for (int b = 0; b < 3; ++b)
          radial[a*3+b] = cd[a*3]*cd[b*3] + cd[a*3+1]*cd[b*3+1] + cd[a*3+2]*cd[b*3+2];
      int j0 = lane, j1 = lane + 64;
      float v0 = kv_load<KB>(kvn, c*KV + 2*j0+1);
      float v1 = kv_load<KB>(kvn, c*KV + 2*j1+1);
      #pragma unroll
      for (int p = 0; p < 9; ++p) {
        v0 += radial[p]*Wkv[p*KV + 2*j0+1];
        v1 += radial[p]*Wkv[p*KV + 2*j1+1];
      }
      if ((j0 >> 5) == quarter) atomicAdd(&agg[(size_t)r*H + j0], alpha_n*v0);
      if ((j1 >> 5) == quarter) atomicAdd(&agg[(size_t)r*H + j1], alpha_n*v1);
      if (quarter == 0 && lane == 0) alpha_out[e] = alpha_n;
      vw[j0] = v0; vw[j1] = v1;
    }
    __syncthreads();
    if (active) {
      float s0 = 0.f, s1 = 0.f;
      #pragma unroll 8
      for (int j2 = 0; j2 < 64; ++j2) {
        float2 vv = vw2[j2];
        unsigned ua = w2[(j2 << 7) + lane];
        unsigned ub = w2[(j2 << 7) + lane + 64];
        s0 += vv.x * __uint_as_float(ua << 16) + vv.y * __uint_as_float(ua & 0xffff0000u);
        s1 += vv.x * __uint_as_float(ub << 16) + vv.y * __uint_as_float(ub & 0xffff0000u);
      }
      s0 = s0 / (1.f + __expf(-s0));   // silu
      s1 = s1 / (1.f + __expf(-s1));
      float cv0 = s0*wc2q[lane*3+0] + s1*wc2q[(lane+64)*3+0];
      float cv1 = s0*wc2q[lane*3+1] + s1*wc2q[(lane+64)*3+1];
      float cv2 = s0*wc2q[lane*3+2] + s1*wc2q[(lane+64)*3+2];
      #pragma unroll
      for (int m = 32; m > 0; m >>= 1) {
        cv0 += __shfl_xor(cv0, m, 64);
        cv1 += __shfl_xor(cv1, m, 64);
        cv2 += __shfl_xor(cv2, m, 64);
      }
      if (lane == 0) {
        float g0 = alpha_n*cv0, g1 = alpha_n*cv1, g2 = alpha_n*cv2;
        float* cg = cagg + (size_t)r*9;
        atomicAdd(cg+0, g0*cd[0]); atomicAdd(cg+1, g0*cd[1]); atomicAdd(cg+2, g0*cd[2]);
        atomicAdd(cg+3, g1*cd[3]); atomicAdd(cg+4, g1*cd[4]); atomicAdd(cg+5, g1*cd[5]);
        atomicAdd(cg+6, g2*cd[6]); atomicAdd(cg+7, g2*cd[7]); atomicAdd(cg+8, g2*cd[8]);
      }
    }
    __syncthreads();
  }
}

// K5: h_out = h + agg ; coord_out = coord + clip(cagg, +/-10)
__global__ __launch_bounds__(256) void k_finalize(
    const float* __restrict__ h, const float* __restrict__ coord,
    const float* __restrict__ agg, const float* __restrict__ cagg,
    float* __restrict__ hout, float* __restrict__ cout, int N)
{
  int i = blockIdx.x*256 + threadIdx.x;
  if (i < N*H) {
    float a = agg[i];
    if (!(a == a)) a = 777.0f;   // NaN marker: accumulator corruption
    hout[i] = h[i] + a;
  }
  if (i < N*9) {
    float x = cagg[i];
    if (!(x == x)) x = 888.0f;
    else x = fminf(10.f, fmaxf(-10.f, x));
    cout[i] = coord[i] + x;
  }
}

template<bool KB>
static void run_pipeline(const float* h, const float* coord,
                         const int* row, const int* col,
                         const float* Wq, const float* bq,
                         const float* Wkv, const float* bkv,
                         const float* Wc1, const float* Wc2,
                         void* d_ws, float* out, int N, int E,
                         hipStream_t stream)
{
  // ws carve: kvn | alpha_ws | segmax | segsum | cagg | qa(qn~agg aliased)
  char* p = (char*)d_ws;
  void* kvn = p;                 p += (size_t)N*KV*(KB ? 2 : 4);
  float* alpha_ws = (float*)p;   p += (size_t)E*4;
  unsigned* segmax = (unsigned*)p; p += (size_t)N*4;
  float* segsum = (float*)p;     p += (size_t)N*4;
  float* cagg = (float*)p;       p += (size_t)N*9*4;
  float* qa = (float*)p;         // qn for K1/K2, then zeroed and reused as agg

  float* hout = out;
  float* cout = out + (size_t)N*H;
  float* aout = cout + (size_t)N*9;

  const int nz1 = N*(1+1+9);     // segmax|segsum|cagg contiguous
  k_zero<<<(nz1 + 255)/256, 256, 0, stream>>>((float*)segmax, nz1);
  k_node_proj<KB><<<(N + 3)/4, 384, 0, stream>>>(h, Wq, bq, Wkv, bkv, qa, kvn, N);
  k_edge_alpha<KB><<<1024, 256, 0, stream>>>(coord, row, col, Wkv, qa, kvn, alpha_ws, segmax, E);
  k_softmax_exp<<<(E + 255)/256, 256, 0, stream>>>(row, segmax, alpha_ws, segsum, E);
  k_zero<<<(N*H + 255)/256, 256, 0, stream>>>(qa, N*H);   // qn dead -> agg
  k_edge_main<KB><<<1024, 256, 0, stream>>>(coord, row, col, Wkv, Wc1, Wc2, kvn, alpha_ws,
                                            segsum, qa, cagg, aout, E);
  k_finalize<<<(N*H + 255)/256, 256, 0, stream>>>(h, coord, qa, cagg, hout, cout, N);
}

extern "C" void kernel_launch(void* const* d_in, const int* in_sizes, int n_in,
                              void* d_out, int out_size, void* d_ws, size_t ws_size,
                              hipStream_t stream)
{
  const float* h     = (const float*)d_in[0];
  const float* coord = (const float*)d_in[1];
  const int* row = (const int*)d_in[2];
  const int* col = (const int*)d_in[3];
  const float* Wq  = (const float*)d_in[4];
  const float* bq  = (const float*)d_in[5];
  const float* Wkv = (const float*)d_in[6];
  const float* bkv = (const float*)d_in[7];
  const float* Wc1 = (const float*)d_in[8];
  const float* Wc2 = (const float*)d_in[9];
  const int N = in_sizes[0] / H;
  const int E = in_sizes[2];
  float* out = (float*)d_out;

  const size_t fixed = (size_t)E*4 + (size_t)N*4*(1+1+9) + (size_t)N*H*4;
  const size_t need_f32 = (size_t)N*KV*4 + fixed;   // ~81.0 MB
  const size_t need_b16 = (size_t)N*KV*2 + fixed;   // ~55.4 MB

  if (ws_size >= need_f32) {
    run_pipeline<false>(h, coord, row, col, Wq, bq, Wkv, bkv, Wc1, Wc2,
                        d_ws, out, N, E, stream);
  } else if (ws_size >= need_b16) {
    run_pipeline<true>(h, coord, row, col, Wq, bq, Wkv, bkv, Wc1, Wc2,
                       d_ws, out, N, E, stream);
  } else {
    k_sentinel<<<(out_size + 255)/256, 256, 0, stream>>>(out, out_size);
  }
}

// Round 5
// 1330.277 us; speedup vs baseline: 2.6718x; 2.6718x over previous
//
#include <hip/hip_runtime.h>

#define H 128
#define KV 256

typedef short bf16x8 __attribute__((ext_vector_type(8)));
typedef float f32x4 __attribute__((ext_vector_type(4)));
union FragU { uint4 u; bf16x8 s; };

__device__ __forceinline__ float bf2f(unsigned short u) {
  return __uint_as_float(((unsigned)u) << 16);
}
__device__ __forceinline__ unsigned short f2bf(float f) {
  unsigned b = __float_as_uint(f);
  b += 0x7FFFu + ((b >> 16) & 1u);   // round-to-nearest-even
  return (unsigned short)(b >> 16);
}
// order-preserving float<->uint for atomicMax-based segment max
__device__ __forceinline__ unsigned f2s(float f) {
  unsigned b = __float_as_uint(f);
  return (b & 0x80000000u) ? ~b : (b | 0x80000000u);
}
__device__ __forceinline__ float s2f(unsigned u) {
  unsigned b = (u & 0x80000000u) ? (u ^ 0x80000000u) : ~u;
  return __uint_as_float(b);
}

// kvn storage: fp32 (KB=false) or bf16 (KB=true)
template<bool KB>
__device__ __forceinline__ float kv_load(const void* kvn, int idx) {
  if (KB) return bf2f(((const unsigned short*)kvn)[idx]);
  else    return ((const float*)kvn)[idx];
}
template<bool KB>
__device__ __forceinline__ void kv_store(void* kvn, int idx, float v) {
  if (KB) ((unsigned short*)kvn)[idx] = f2bf(v);
  else    ((float*)kvn)[idx] = v;
}

__global__ __launch_bounds__(256) void k_zero(float* __restrict__ p, int n) {
  int i = blockIdx.x * 256 + threadIdx.x;
  if (i < n) p[i] = 0.f;
}

__global__ __launch_bounds__(256) void k_sentinel(float* __restrict__ out, int n) {
  int i = blockIdx.x * 256 + threadIdx.x;
  if (i < n) out[i] = 1000.0f;
}

// pack Wc1 (128x512 fp32) into bf16 B-fragment order:
// w1f[((q*4+kk)*8+ni)*64 + lane] = 8 bf16 of Wc1[k=kk*32+(lane>>4)*8+j][o=q*128+ni*16+(lane&15)]
__global__ __launch_bounds__(256) void k_prep_w1(const float* __restrict__ Wc1,
                                                 uint4* __restrict__ w1f) {
  int t = blockIdx.x*256 + threadIdx.x;    // 8192 total
  int g = t >> 6, lane = t & 63;
  int q = g >> 5, kk = (g >> 3) & 3, ni = g & 7;
  int o = q*128 + ni*16 + (lane & 15);
  int kbase = kk*32 + (lane >> 4)*8;
  unsigned s[8];
  #pragma unroll
  for (int j = 0; j < 8; ++j) s[j] = f2bf(Wc1[(kbase+j)*512 + o]);
  uint4 u;
  u.x = s[0] | (s[1]<<16); u.y = s[2] | (s[3]<<16);
  u.z = s[4] | (s[5]<<16); u.w = s[6] | (s[7]<<16);
  w1f[g*64 + lane] = u;
}

// K1: qn = h@Wq + bq (N x 128), kvn = h@Wkv[9:,:] + bkv (N x 256); 4 nodes/block
template<bool KB>
__global__ __launch_bounds__(384) void k_node_proj(
    const float* __restrict__ h, const float* __restrict__ Wq,
    const float* __restrict__ bq, const float* __restrict__ Wkv,
    const float* __restrict__ bkv, float* __restrict__ qn,
    void* __restrict__ kvn, int N)
{
  __shared__ float hs[4][H];
  const int n0 = blockIdx.x * 4;
  const int t = threadIdx.x;
  for (int idx = t; idx < 4*H; idx += 384) {
    int nn = idx >> 7, jj = idx & 127;
    hs[nn][jj] = (n0 + nn < N) ? h[(size_t)(n0+nn)*H + jj] : 0.f;
  }
  __syncthreads();
  float a0 = 0.f, a1 = 0.f, a2 = 0.f, a3 = 0.f;
  if (t < H) {
    #pragma unroll 4
    for (int j = 0; j < H; ++j) {
      float w = Wq[j*H + t];
      a0 += hs[0][j]*w; a1 += hs[1][j]*w; a2 += hs[2][j]*w; a3 += hs[3][j]*w;
    }
    float b = bq[t];
    if (n0+0 < N) qn[(size_t)(n0+0)*H + t] = a0 + b;
    if (n0+1 < N) qn[(size_t)(n0+1)*H + t] = a1 + b;
    if (n0+2 < N) qn[(size_t)(n0+2)*H + t] = a2 + b;
    if (n0+3 < N) qn[(size_t)(n0+3)*H + t] = a3 + b;
  } else {
    int c = t - H;
    #pragma unroll 4
    for (int j = 0; j < H; ++j) {
      float w = Wkv[(9 + j)*KV + c];
      a0 += hs[0][j]*w; a1 += hs[1][j]*w; a2 += hs[2][j]*w; a3 += hs[3][j]*w;
    }
    float b = bkv[c];
    if (n0+0 < N) kv_store<KB>(kvn, (n0+0)*KV + c, a0 + b);
    if (n0+1 < N) kv_store<KB>(kvn, (n0+1)*KV + c, a1 + b);
    if (n0+2 < N) kv_store<KB>(kvn, (n0+2)*KV + c, a2 + b);
    if (n0+3 < N) kv_store<KB>(kvn, (n0+3)*KV + c, a3 + b);
  }
}

// K2: per-edge alpha_raw = q . k (wave per edge), segment max via sortable atomicMax
template<bool KB>
__global__ __launch_bounds__(256) void k_edge_alpha(
    const float* __restrict__ coord, const int* __restrict__ row,
    const int* __restrict__ col, const float* __restrict__ Wkv,
    const float* __restrict__ qn, const void* __restrict__ kvn,
    float* __restrict__ alpha_ws, unsigned* __restrict__ segmax, int E)
{
  int lane = threadIdx.x & 63;
  int gw = (blockIdx.x * blockDim.x + threadIdx.x) >> 6;
  int nw = (gridDim.x * blockDim.x) >> 6;
  for (int e = gw; e < E; e += nw) {
    int r = row[e], c = col[e];
    float cd[9], radial[9];
    const float* cr = coord + (size_t)r*9;
    const float* cc = coord + (size_t)c*9;
    #pragma unroll
    for (int i = 0; i < 9; ++i) cd[i] = cr[i] - cc[i];
    #pragma unroll
    for (int a = 0; a < 3; ++a)
      #pragma unroll
      for (int b = 0; b < 3; ++b)
        radial[a*3+b] = cd[a*3]*cd[b*3] + cd[a*3+1]*cd[b*3+1] + cd[a*3+2]*cd[b*3+2];
    const float* q = qn + (size_t)r*H;
    float acc = 0.f;
    #pragma unroll
    for (int t = 0; t < 2; ++t) {
      int j = lane + 64*t;
      float kj = kv_load<KB>(kvn, c*KV + 2*j);   // bkv already folded into kvn
      #pragma unroll
      for (int p = 0; p < 9; ++p) kj += radial[p] * Wkv[p*KV + 2*j];
      acc += q[j] * kj;
    }
    #pragma unroll
    for (int m = 32; m > 0; m >>= 1) acc += __shfl_xor(acc, m, 64);
    if (lane == 0) {
      alpha_ws[e] = acc;
      atomicMax(&segmax[r], f2s(acc));
    }
  }
}

// K3: ex = exp(min(alpha - segmax[row], 0)); segsum += ex
__global__ __launch_bounds__(256) void k_softmax_exp(
    const int* __restrict__ row, const unsigned* __restrict__ segmax,
    float* __restrict__ alpha_ws, float* __restrict__ segsum, int E)
{
  int e = blockIdx.x * 256 + threadIdx.x;
  if (e >= E) return;
  int r = row[e];
  float d = alpha_ws[e] - s2f(segmax[r]);
  float ex = __expf(fminf(d, 0.f));
  alpha_ws[e] = ex;
  atomicAdd(&segsum[r], ex);
}

// K4-MFMA: one block per 128-edge tile.
// P1: per-edge cd/radial/alpha/r/c -> LDS. P2: V (128x128) -> swizzled bf16 LDS
// tile + agg atomics. P3: 4 o-quarters of hidden = Vt @ Wc1q via mfma 16x16x32,
// silu + xWc2 in-register (butterfly over the 16 C-layout cols), cagg atomics.
__global__ __launch_bounds__(256) void k_edge_mfma(
    const float* __restrict__ coord, const int* __restrict__ row,
    const int* __restrict__ col, const float* __restrict__ Wkv,
    const float* __restrict__ Wc2, const float* __restrict__ kvn,
    const uint4* __restrict__ w1f, const float* __restrict__ alpha_ws,
    const float* __restrict__ segsum, float* __restrict__ agg,
    float* __restrict__ cagg, float* __restrict__ alpha_out, int E)
{
  __shared__ unsigned vt[128*64];     // 32KB: V tile bf16x2, 16B-chunk XOR swizzle
  __shared__ float einfo[128*21];     // cd[9] | radial[9] | alpha | r | c
  __shared__ float wkvo[9*128];       // Wkv odd columns (v part)
  __shared__ float wc2s[512*3];       // full Wc2
  const int tid = threadIdx.x;
  const int wid = tid >> 6, lane = tid & 63;
  const int quad = lane >> 4, colc = lane & 15;

  for (int idx = tid; idx < 9*128; idx += 256) {
    int p = idx >> 7, j = idx & 127;
    wkvo[idx] = Wkv[p*KV + 2*j + 1];
  }
  for (int idx = tid; idx < 512*3; idx += 256) wc2s[idx] = Wc2[idx];

  // ---- phase 1: edge info ----
  const int e0 = blockIdx.x * 128;
  if (tid < 128) {
    int e = e0 + tid;
    float* ei = &einfo[tid*21];
    if (e < E) {
      int r = row[e], c = col[e];
      float cd[9];
      #pragma unroll
      for (int i = 0; i < 9; ++i) cd[i] = coord[(size_t)r*9+i] - coord[(size_t)c*9+i];
      #pragma unroll
      for (int i = 0; i < 9; ++i) ei[i] = cd[i];
      #pragma unroll
      for (int a = 0; a < 3; ++a)
        #pragma unroll
        for (int b = 0; b < 3; ++b)
          ei[9 + a*3+b] = cd[a*3]*cd[b*3] + cd[a*3+1]*cd[b*3+1] + cd[a*3+2]*cd[b*3+2];
      float al = alpha_ws[e] / fmaxf(segsum[r], 1e-30f);
      ei[18] = al;
      ei[19] = __int_as_float(r);
      ei[20] = __int_as_float(c);
      alpha_out[e] = al;
    } else {
      #pragma unroll
      for (int i = 0; i < 21; ++i) ei[i] = 0.f;   // alpha=0, r=c=0 -> inert
    }
  }
  __syncthreads();

  // ---- phase 2: V tile + agg atomics (each wave: one edge per iteration) ----
  const float4* kvn4 = (const float4*)kvn;
  const float2* wk2 = (const float2*)wkvo;
  for (int i = 0; i < 32; ++i) {
    int el = i*4 + wid;
    const float* ei = &einfo[el*21];
    float rad[9];
    #pragma unroll
    for (int p = 0; p < 9; ++p) rad[p] = ei[9+p];
    float al = ei[18];
    int r = __float_as_int(ei[19]);
    int c = __float_as_int(ei[20]);
    float4 kv4 = kvn4[(size_t)c*64 + lane];   // elements 4*lane .. 4*lane+3
    float v0 = kv4.y, v1 = kv4.w;             // v_j for j=2*lane, 2*lane+1
    #pragma unroll
    for (int p = 0; p < 9; ++p) {
      float2 w = wk2[p*64 + lane];
      v0 += rad[p]*w.x; v1 += rad[p]*w.y;
    }
    atomicAdd(&agg[(size_t)r*H + 2*lane],     al*v0);
    atomicAdd(&agg[(size_t)r*H + 2*lane + 1], al*v1);
    unsigned pk = (unsigned)f2bf(v0) | ((unsigned)f2bf(v1) << 16);
    vt[el*64 + (((lane>>2) ^ (el&15))<<2) + (lane&3)] = pk;
  }
  __syncthreads();

  // ---- phase 3: MFMA GEMM per o-quarter + epilogue ----
  const int mrow = wid*32;   // wave owns edges [mrow, mrow+32)
  for (int q = 0; q < 4; ++q) {
    f32x4 acc[2][8];
    #pragma unroll
    for (int a = 0; a < 2; ++a)
      #pragma unroll
      for (int n = 0; n < 8; ++n) acc[a][n] = (f32x4){0.f,0.f,0.f,0.f};
    #pragma unroll
    for (int kk = 0; kk < 4; ++kk) {
      FragU bfr[8];
      #pragma unroll
      for (int n = 0; n < 8; ++n)
        bfr[n].u = w1f[(((q*4+kk)*8+n)<<6) + lane];
      FragU afr[2];
      #pragma unroll
      for (int a = 0; a < 2; ++a) {
        int rrow = mrow + a*16 + colc;
        int chunk = kk*4 + quad;
        afr[a].u = *((const uint4*)&vt[rrow*64 + ((chunk ^ (rrow&15))<<2)]);
      }
      #pragma unroll
      for (int a = 0; a < 2; ++a)
        #pragma unroll
        for (int n = 0; n < 8; ++n)
          acc[a][n] = __builtin_amdgcn_mfma_f32_16x16x32_bf16(
              afr[a].s, bfr[n].s, acc[a][n], 0, 0, 0);
    }
    // epilogue: silu, multiply by Wc2 col, reduce over o (cols), cagg atomics
    float wch[8][3];
    #pragma unroll
    for (int n = 0; n < 8; ++n) {
      int o = q*128 + n*16 + colc;
      wch[n][0] = wc2s[o*3+0]; wch[n][1] = wc2s[o*3+1]; wch[n][2] = wc2s[o*3+2];
    }
    float part[2][4][3];
    #pragma unroll
    for (int a=0;a<2;++a)
      #pragma unroll
      for (int g=0;g<4;++g) { part[a][g][0]=0.f; part[a][g][1]=0.f; part[a][g][2]=0.f; }
    #pragma unroll
    for (int a = 0; a < 2; ++a)
      #pragma unroll
      for (int n = 0; n < 8; ++n)
        #pragma unroll
        for (int g = 0; g < 4; ++g) {
          float s = acc[a][n][g];
          float hs = s / (1.f + __expf(-s));   // silu
          part[a][g][0] += hs*wch[n][0];
          part[a][g][1] += hs*wch[n][1];
          part[a][g][2] += hs*wch[n][2];
        }
    #pragma unroll
    for (int off = 1; off < 16; off <<= 1)
      #pragma unroll
      for (int a=0;a<2;++a)
        #pragma unroll
        for (int g=0;g<4;++g) {
          part[a][g][0] += __shfl_xor(part[a][g][0], off, 64);
          part[a][g][1] += __shfl_xor(part[a][g][1], off, 64);
          part[a][g][2] += __shfl_xor(part[a][g][2], off, 64);
        }
    if (colc < 3) {
      int ch = colc;
      #pragma unroll
      for (int a = 0; a < 2; ++a)
        #pragma unroll
        for (int g = 0; g < 4; ++g) {
          int el = mrow + a*16 + quad*4 + g;    // C-layout row
          const float* ei = &einfo[el*21];
          float al = ei[18];
          int r = __float_as_int(ei[19]);
          float gg = al * part[a][g][ch];
          float* cg = &cagg[(size_t)r*9 + ch*3];
          atomicAdd(cg+0, gg*ei[ch*3+0]);
          atomicAdd(cg+1, gg*ei[ch*3+1]);
          atomicAdd(cg+2, gg*ei[ch*3+2]);
        }
    }
  }
}

// Fallback K4 (scalar) for small-ws tiers
template<bool KB>
__global__ __launch_bounds__(256) void k_edge_main(
    const float* __restrict__ coord, const int* __restrict__ row,
    const int* __restrict__ col, const float* __restrict__ Wkv,
    const float* __restrict__ Wc1, const float* __restrict__ Wc2,
    const void* __restrict__ kvn, const float* __restrict__ alpha_ws,
    const float* __restrict__ segsum, float* __restrict__ agg,
    float* __restrict__ cagg, float* __restrict__ alpha_out, int E)
{
  __shared__ unsigned w2[64*128];
  __shared__ float wc2q[128*3];
  __shared__ float vsh[4][128];
  const int quarter = blockIdx.x & 3;
  const int obase = quarter << 7;
  const int tid = threadIdx.x;
  const float* Wc1q = Wc1 + obase;
  for (int idx = tid; idx < 64*128; idx += 256) {
    int j2 = idx >> 7, o = idx & 127;
    unsigned lo = f2bf(Wc1q[(2*j2)*512 + o]);
    unsigned hi = f2bf(Wc1q[(2*j2+1)*512 + o]);
    w2[idx] = lo | (hi << 16);
  }
  for (int idx = tid; idx < 128*3; idx += 256)
    wc2q[idx] = Wc2[obase*3 + idx];
  __syncthreads();
  const int wid = tid >> 6, lane = tid & 63;
  const int gw = (blockIdx.x >> 2)*4 + wid;
  const int nw = gridDim.x;
  const int iters = (E + nw - 1)/nw;
  float* vw = vsh[wid];
  const float2* vw2 = (const float2*)vw;
  for (int it = 0; it < iters; ++it) {
    int e = gw + it*nw;
    bool active = e < E;
    int r = 0;
    float alpha_n = 0.f, cd[9];
    if (active) {
      r = row[e];
      int c = col[e];
      alpha_n = alpha_ws[e] / fmaxf(segsum[r], 1e-30f);
      const float* crd = coord + (size_t)r*9;
      const float* ccd = coord + (size_t)c*9;
      float radial[9];
      #pragma unroll
      for (int i = 0; i < 9; ++i) cd[i] = crd[i] - ccd[i];
      #pragma unroll
      for (int a = 0; a < 3; ++a)
        #pragma unroll
        for (int b = 0; b < 3; ++b)
          radial[a*3+b] = cd[a*3]*cd[b*3] + cd[a*3+1]*cd[b*3+1] + cd[a*3+2]*cd[b*3+2];
      int j0 = lane, j1 = lane + 64;
      float v0 = kv_load<KB>(kvn, c*KV + 2*j0+1);
      float v1 = kv_load<KB>(kvn, c*KV + 2*j1+1);
      #pragma unroll
      for (int p = 0; p < 9; ++p) {
        v0 += radial[p]*Wkv[p*KV + 2*j0+1];
        v1 += radial[p]*Wkv[p*KV + 2*j1+1];
      }
      if ((j0 >> 5) == quarter) atomicAdd(&agg[(size_t)r*H + j0], alpha_n*v0);
      if ((j1 >> 5) == quarter) atomicAdd(&agg[(size_t)r*H + j1], alpha_n*v1);
      if (quarter == 0 && lane == 0) alpha_out[e] = alpha_n;
      vw[j0] = v0; vw[j1] = v1;
    }
    __syncthreads();
    if (active) {
      float s0 = 0.f, s1 = 0.f;
      #pragma unroll 8
      for (int j2 = 0; j2 < 64; ++j2) {
        float2 vv = vw2[j2];
        unsigned ua = w2[(j2 << 7) + lane];
        unsigned ub = w2[(j2 << 7) + lane + 64];
        s0 += vv.x * __uint_as_float(ua << 16) + vv.y * __uint_as_float(ua & 0xffff0000u);
        s1 += vv.x * __uint_as_float(ub << 16) + vv.y * __uint_as_float(ub & 0xffff0000u);
      }
      s0 = s0 / (1.f + __expf(-s0));
      s1 = s1 / (1.f + __expf(-s1));
      float cv0 = s0*wc2q[lane*3+0] + s1*wc2q[(lane+64)*3+0];
      float cv1 = s0*wc2q[lane*3+1] + s1*wc2q[(lane+64)*3+1];
      float cv2 = s0*wc2q[lane*3+2] + s1*wc2q[(lane+64)*3+2];
      #pragma unroll
      for (int m = 32; m > 0; m >>= 1) {
        cv0 += __shfl_xor(cv0, m, 64);
        cv1 += __shfl_xor(cv1, m, 64);
        cv2 += __shfl_xor(cv2, m, 64);
      }
      if (lane == 0) {
        float g0 = alpha_n*cv0, g1 = alpha_n*cv1, g2 = alpha_n*cv2;
        float* cg = cagg + (size_t)r*9;
        atomicAdd(cg+0, g0*cd[0]); atomicAdd(cg+1, g0*cd[1]); atomicAdd(cg+2, g0*cd[2]);
        atomicAdd(cg+3, g1*cd[3]); atomicAdd(cg+4, g1*cd[4]); atomicAdd(cg+5, g1*cd[5]);
        atomicAdd(cg+6, g2*cd[6]); atomicAdd(cg+7, g2*cd[7]); atomicAdd(cg+8, g2*cd[8]);
      }
    }
    __syncthreads();
  }
}

// K5: h_out = h + agg ; coord_out = coord + clip(cagg, +/-10)
__global__ __launch_bounds__(256) void k_finalize(
    const float* __restrict__ h, const float* __restrict__ coord,
    const float* __restrict__ agg, const float* __restrict__ cagg,
    float* __restrict__ hout, float* __restrict__ cout, int N)
{
  int i = blockIdx.x*256 + threadIdx.x;
  if (i < N*H) {
    float a = agg[i];
    if (!(a == a)) a = 777.0f;
    hout[i] = h[i] + a;
  }
  if (i < N*9) {
    float x = cagg[i];
    if (!(x == x)) x = 888.0f;
    else x = fminf(10.f, fmaxf(-10.f, x));
    cout[i] = coord[i] + x;
  }
}

template<bool KB>
static void run_pipeline(const float* h, const float* coord,
                         const int* row, const int* col,
                         const float* Wq, const float* bq,
                         const float* Wkv, const float* bkv,
                         const float* Wc1, const float* Wc2,
                         void* d_ws, float* out, int N, int E, bool use_mfma,
                         hipStream_t stream)
{
  // ws carve: kvn | alpha_ws | segmax | segsum | cagg | qa(qn~agg) | w1frag
  char* p = (char*)d_ws;
  void* kvn = p;                   p += (size_t)N*KV*(KB ? 2 : 4);
  float* alpha_ws = (float*)p;     p += (size_t)E*4;
  unsigned* segmax = (unsigned*)p; p += (size_t)N*4;
  float* segsum = (float*)p;       p += (size_t)N*4;
  float* cagg = (float*)p;         p += (size_t)N*9*4;
  float* qa = (float*)p;           p += (size_t)N*H*4;
  uint4* w1f = (uint4*)((((size_t)p) + 15) & ~(size_t)15);

  float* hout = out;
  float* cout = out + (size_t)N*H;
  float* aout = cout + (size_t)N*9;

  const int nz1 = N*(1+1+9);
  k_zero<<<(nz1 + 255)/256, 256, 0, stream>>>((float*)segmax, nz1);
  if (use_mfma) k_prep_w1<<<32, 256, 0, stream>>>(Wc1, w1f);
  k_node_proj<KB><<<(N + 3)/4, 384, 0, stream>>>(h, Wq, bq, Wkv, bkv, qa, kvn, N);
  k_edge_alpha<KB><<<1024, 256, 0, stream>>>(coord, row, col, Wkv, qa, kvn, alpha_ws, segmax, E);
  k_softmax_exp<<<(E + 255)/256, 256, 0, stream>>>(row, segmax, alpha_ws, segsum, E);
  k_zero<<<(N*H + 255)/256, 256, 0, stream>>>(qa, N*H);   // qn dead -> agg
  if (use_mfma) {
    k_edge_mfma<<<(E + 127)/128, 256, 0, stream>>>(coord, row, col, Wkv, Wc2,
        (const float*)kvn, w1f, alpha_ws, segsum, qa, cagg, aout, E);
  } else {
    k_edge_main<KB><<<1024, 256, 0, stream>>>(coord, row, col, Wkv, Wc1, Wc2, kvn,
        alpha_ws, segsum, qa, cagg, aout, E);
  }
  k_finalize<<<(N*H + 255)/256, 256, 0, stream>>>(h, coord, qa, cagg, hout, cout, N);
}

extern "C" void kernel_launch(void* const* d_in, const int* in_sizes, int n_in,
                              void* d_out, int out_size, void* d_ws, size_t ws_size,
                              hipStream_t stream)
{
  const float* h     = (const float*)d_in[0];
  const float* coord = (const float*)d_in[1];
  const int* row = (const int*)d_in[2];
  const int* col = (const int*)d_in[3];
  const float* Wq  = (const float*)d_in[4];
  const float* bq  = (const float*)d_in[5];
  const float* Wkv = (const float*)d_in[6];
  const float* bkv = (const float*)d_in[7];
  const float* Wc1 = (const float*)d_in[8];
  const float* Wc2 = (const float*)d_in[9];
  const int N = in_sizes[0] / H;
  const int E = in_sizes[2];
  float* out = (float*)d_out;

  const size_t fixed = (size_t)E*4 + (size_t)N*4*(1+1+9) + (size_t)N*H*4;
  const size_t need_mfma = (size_t)N*KV*4 + fixed + (1<<17) + 16;  // +128KB w1frag
  const size_t need_f32  = (size_t)N*KV*4 + fixed;                 // ~81.0 MB
  const size_t need_b16  = (size_t)N*KV*2 + fixed;                 // ~55.4 MB

  if (ws_size >= need_mfma) {
    run_pipeline<false>(h, coord, row, col, Wq, bq, Wkv, bkv, Wc1, Wc2,
                        d_ws, out, N, E, true, stream);
  } else if (ws_size >= need_f32) {
    run_pipeline<false>(h, coord, row, col, Wq, bq, Wkv, bkv, Wc1, Wc2,
                        d_ws, out, N, E, false, stream);
  } else if (ws_size >= need_b16) {
    run_pipeline<true>(h, coord, row, col, Wq, bq, Wkv, bkv, Wc1, Wc2,
                       d_ws, out, N, E, false, stream);
  } else {
    k_sentinel<<<(out_size + 255)/256, 256, 0, stream>>>(out, out_size);
  }
}

// Round 6
// 1104.137 us; speedup vs baseline: 3.2190x; 1.2048x over previous
//
#include <hip/hip_runtime.h>

#define H 128
#define KV 256

typedef short bf16x8 __attribute__((ext_vector_type(8)));
typedef float f32x4 __attribute__((ext_vector_type(4)));
union FragU { uint4 u; bf16x8 s; };

__device__ __forceinline__ float bf2f(unsigned short u) {
  return __uint_as_float(((unsigned)u) << 16);
}
__device__ __forceinline__ unsigned short f2bf(float f) {
  unsigned b = __float_as_uint(f);
  b += 0x7FFFu + ((b >> 16) & 1u);   // round-to-nearest-even
  return (unsigned short)(b >> 16);
}

// node-array storage: fp32 (KB=false) or bf16 (KB=true) tier
template<bool KB>
__device__ __forceinline__ float nld(const void* a, size_t idx) {
  if (KB) return bf2f(((const unsigned short*)a)[idx]);
  else    return ((const float*)a)[idx];
}
template<bool KB>
__device__ __forceinline__ void nst(void* a, size_t idx, float v) {
  if (KB) ((unsigned short*)a)[idx] = f2bf(v);
  else    ((float*)a)[idx] = v;
}

__global__ __launch_bounds__(256) void k_zero(float* __restrict__ p, int n) {
  int i = blockIdx.x * 256 + threadIdx.x;
  if (i < n) p[i] = 0.f;
}

__global__ __launch_bounds__(256) void k_sentinel(float* __restrict__ out, int n) {
  int i = blockIdx.x * 256 + threadIdx.x;
  if (i < n) out[i] = 1000.0f;
}

// pack Wc1 (128x512 fp32) into bf16 B-fragment order for mfma 16x16x32
__global__ __launch_bounds__(256) void k_prep_w1(const float* __restrict__ Wc1,
                                                 uint4* __restrict__ w1f) {
  int t = blockIdx.x*256 + threadIdx.x;    // 8192 total
  int g = t >> 6, lane = t & 63;
  int q = g >> 5, kk = (g >> 3) & 3, ni = g & 7;
  int o = q*128 + ni*16 + (lane & 15);
  int kbase = kk*32 + (lane >> 4)*8;
  unsigned s[8];
  #pragma unroll
  for (int j = 0; j < 8; ++j) s[j] = f2bf(Wc1[(kbase+j)*512 + o]);
  uint4 u;
  u.x = s[0] | (s[1]<<16); u.y = s[2] | (s[3]<<16);
  u.z = s[4] | (s[5]<<16); u.w = s[6] | (s[7]<<16);
  w1f[g*64 + lane] = u;
}

// ---------- counting sort of edges by row ----------
__global__ __launch_bounds__(256) void k_hist(const int* __restrict__ row,
                                              int* __restrict__ counts, int E) {
  int e = blockIdx.x*256 + threadIdx.x;
  if (e < E) atomicAdd(&counts[row[e]], 1);
}

// single-block exclusive scan (wave-scan + cross-wave), also inits cursor
__global__ __launch_bounds__(1024) void k_scan(const int* __restrict__ counts,
                                               int* __restrict__ row_start,
                                               int* __restrict__ cursor, int n) {
  __shared__ int wsum[16];
  __shared__ int carry_s;
  const int tid = threadIdx.x, lane = tid & 63, wid = tid >> 6;
  if (tid == 0) carry_s = 0;
  __syncthreads();
  for (int base = 0; base < n; base += 1024) {
    int i = base + tid;
    int v = (i < n) ? counts[i] : 0;
    int s = v;
    #pragma unroll
    for (int off = 1; off < 64; off <<= 1) {
      int t = __shfl_up(s, off, 64);
      if (lane >= off) s += t;
    }
    if (lane == 63) wsum[wid] = s;
    __syncthreads();
    if (wid == 0 && lane < 16) {
      int w = wsum[lane];
      #pragma unroll
      for (int off = 1; off < 16; off <<= 1) {
        int t = __shfl_up(w, off, 16);
        if (lane >= off) w += t;
      }
      wsum[lane] = w;
    }
    __syncthreads();
    int wexcl = (wid == 0) ? 0 : wsum[wid-1];
    int excl = carry_s + wexcl + (s - v);
    if (i < n) { row_start[i] = excl; cursor[i] = excl; }
    __syncthreads();
    if (tid == 0) carry_s += wsum[15];
    __syncthreads();
  }
  if (threadIdx.x == 0) row_start[n] = carry_s;
}

__global__ __launch_bounds__(256) void k_scatter(const int* __restrict__ row,
                                                 int* __restrict__ cursor,
                                                 int* __restrict__ eidx, int E) {
  int e = blockIdx.x*256 + threadIdx.x;
  if (e < E) {
    int pos = atomicAdd(&cursor[row[e]], 1);
    eidx[pos] = e;
  }
}

// ---------- K1: qn = h@Wq+bq, kn/vn = deinterleaved h@Wkv[9:]+bkv ----------
template<bool KB>
__global__ __launch_bounds__(384) void k_node_proj(
    const float* __restrict__ h, const float* __restrict__ Wq,
    const float* __restrict__ bq, const float* __restrict__ Wkv,
    const float* __restrict__ bkv, void* __restrict__ qn,
    void* __restrict__ kn, void* __restrict__ vn, int N)
{
  __shared__ float hs[4][H];
  const int n0 = blockIdx.x * 4;
  const int t = threadIdx.x;
  for (int idx = t; idx < 4*H; idx += 384) {
    int nn = idx >> 7, jj = idx & 127;
    hs[nn][jj] = (n0 + nn < N) ? h[(size_t)(n0+nn)*H + jj] : 0.f;
  }
  __syncthreads();
  float a0 = 0.f, a1 = 0.f, a2 = 0.f, a3 = 0.f;
  if (t < H) {
    #pragma unroll 4
    for (int j = 0; j < H; ++j) {
      float w = Wq[j*H + t];
      a0 += hs[0][j]*w; a1 += hs[1][j]*w; a2 += hs[2][j]*w; a3 += hs[3][j]*w;
    }
    float b = bq[t];
    if (n0+0 < N) nst<KB>(qn, (size_t)(n0+0)*H + t, a0 + b);
    if (n0+1 < N) nst<KB>(qn, (size_t)(n0+1)*H + t, a1 + b);
    if (n0+2 < N) nst<KB>(qn, (size_t)(n0+2)*H + t, a2 + b);
    if (n0+3 < N) nst<KB>(qn, (size_t)(n0+3)*H + t, a3 + b);
  } else {
    int c = t - H;                 // column of 2H kv output
    #pragma unroll 4
    for (int j = 0; j < H; ++j) {
      float w = Wkv[(9 + j)*KV + c];
      a0 += hs[0][j]*w; a1 += hs[1][j]*w; a2 += hs[2][j]*w; a3 += hs[3][j]*w;
    }
    float b = bkv[c];
    void* dst = (c & 1) ? vn : kn;
    size_t ch = (size_t)(c >> 1);
    if (n0+0 < N) nst<KB>(dst, (size_t)(n0+0)*H + ch, a0 + b);
    if (n0+1 < N) nst<KB>(dst, (size_t)(n0+1)*H + ch, a1 + b);
    if (n0+2 < N) nst<KB>(dst, (size_t)(n0+2)*H + ch, a2 + b);
    if (n0+3 < N) nst<KB>(dst, (size_t)(n0+3)*H + ch, a3 + b);
  }
}

// ---------- K2: raw alpha per edge -> aout ----------
template<bool KB>
__global__ __launch_bounds__(256) void k_edge_alpha(
    const float* __restrict__ coord, const int* __restrict__ row,
    const int* __restrict__ col, const float* __restrict__ Wkv,
    const void* __restrict__ qn, const void* __restrict__ kn,
    float* __restrict__ aout, int E)
{
  __shared__ float wke[9*128];     // Wkv even cols (k weights for radial)
  const int tid = threadIdx.x;
  for (int idx = tid; idx < 9*128; idx += 256) {
    int p = idx >> 7, j = idx & 127;
    wke[idx] = Wkv[p*KV + 2*j];
  }
  __syncthreads();
  int lane = tid & 63;
  int gw = (blockIdx.x * 256 + tid) >> 6;
  int nw = (gridDim.x * 256) >> 6;
  for (int e = gw; e < E; e += nw) {
    int r = row[e], c = col[e];
    float cd[9], rad[9];
    #pragma unroll
    for (int i = 0; i < 9; ++i) cd[i] = coord[(size_t)r*9+i] - coord[(size_t)c*9+i];
    #pragma unroll
    for (int a = 0; a < 3; ++a)
      #pragma unroll
      for (int b = 0; b < 3; ++b)
        rad[a*3+b] = cd[a*3]*cd[b*3] + cd[a*3+1]*cd[b*3+1] + cd[a*3+2]*cd[b*3+2];
    float q0 = nld<KB>(qn, (size_t)r*H + lane);
    float q1 = nld<KB>(qn, (size_t)r*H + 64 + lane);
    float k0 = nld<KB>(kn, (size_t)c*H + lane);
    float k1 = nld<KB>(kn, (size_t)c*H + 64 + lane);
    #pragma unroll
    for (int p = 0; p < 9; ++p) {
      k0 += rad[p]*wke[p*128 + lane];
      k1 += rad[p]*wke[p*128 + 64 + lane];
    }
    float acc = q0*k0 + q1*k1;
    #pragma unroll
    for (int m = 32; m > 0; m >>= 1) acc += __shfl_xor(acc, m, 64);
    if (lane == 0) aout[e] = acc;
  }
}

// ---------- K3: per-row softmax normalize (CSR, no atomics) ----------
__global__ __launch_bounds__(256) void k_row_softmax(
    const int* __restrict__ row_start, const int* __restrict__ eidx,
    float* __restrict__ aout, int N)
{
  int r = blockIdx.x*256 + threadIdx.x;
  if (r >= N) return;
  int js = row_start[r], je = row_start[r+1];
  if (js >= je) return;
  float m = -1e30f;
  for (int j = js; j < je; ++j) m = fmaxf(m, aout[eidx[j]]);
  float s = 0.f;
  for (int j = js; j < je; ++j) s += __expf(aout[eidx[j]] - m);
  float inv = 1.f / s;              // s >= 1 (max edge contributes exp(0)=1)
  for (int j = js; j < je; ++j) {
    int ie = eidx[j];
    aout[ie] = __expf(aout[ie] - m) * inv;
  }
}

// ---------- K4a: per-row agg (atomic-free) fused with h_out ----------
// agg[r] = sum_e a_e*vn[c_e] + (sum_e a_e*rad_e) @ Wvo ; hout = h + agg
template<bool KB>
__global__ __launch_bounds__(256) void k_agg_row(
    const float* __restrict__ h, const float* __restrict__ coord,
    const int* __restrict__ col, const float* __restrict__ Wkv,
    const int* __restrict__ row_start, const int* __restrict__ eidx,
    const float* __restrict__ aout, const void* __restrict__ vn,
    float* __restrict__ hout, int N)
{
  __shared__ float wvo[9*128];     // Wkv odd cols (v weights for radial)
  const int tid = threadIdx.x;
  for (int idx = tid; idx < 9*128; idx += 256) {
    int p = idx >> 7, j = idx & 127;
    wvo[idx] = Wkv[p*KV + 2*j + 1];
  }
  __syncthreads();
  const int wid = tid >> 6, lane = tid & 63;
  const int r = blockIdx.x*4 + wid;
  if (r >= N) return;
  int js = row_start[r], je = row_start[r+1];
  float cr[9];
  #pragma unroll
  for (int i = 0; i < 9; ++i) cr[i] = coord[(size_t)r*9 + i];
  float acc0 = 0.f, acc1 = 0.f;
  float t[9];
  #pragma unroll
  for (int p = 0; p < 9; ++p) t[p] = 0.f;
  for (int j = js; j < je; ++j) {
    int ie = eidx[j];
    float a = aout[ie];
    int c = col[ie];
    float cd[9], rad[9];
    #pragma unroll
    for (int i = 0; i < 9; ++i) cd[i] = cr[i] - coord[(size_t)c*9+i];
    #pragma unroll
    for (int aa = 0; aa < 3; ++aa)
      #pragma unroll
      for (int bb = 0; bb < 3; ++bb)
        rad[aa*3+bb] = cd[aa*3]*cd[bb*3] + cd[aa*3+1]*cd[bb*3+1] + cd[aa*3+2]*cd[bb*3+2];
    acc0 += a * nld<KB>(vn, (size_t)c*H + 2*lane);
    acc1 += a * nld<KB>(vn, (size_t)c*H + 2*lane + 1);
    #pragma unroll
    for (int p = 0; p < 9; ++p) t[p] += a * rad[p];
  }
  #pragma unroll
  for (int p = 0; p < 9; ++p) {
    acc0 += t[p] * wvo[p*128 + 2*lane];
    acc1 += t[p] * wvo[p*128 + 2*lane + 1];
  }
  hout[(size_t)r*H + 2*lane]     = h[(size_t)r*H + 2*lane]     + acc0;
  hout[(size_t)r*H + 2*lane + 1] = h[(size_t)r*H + 2*lane + 1] + acc1;
}

// ---------- K4b: MFMA MLP per 128-edge tile (no agg atomics) ----------
template<bool KB>
__global__ __launch_bounds__(256) void k_edge_mlp(
    const float* __restrict__ coord, const int* __restrict__ row,
    const int* __restrict__ col, const float* __restrict__ Wkv,
    const float* __restrict__ Wc2, const void* __restrict__ vn,
    const uint4* __restrict__ w1f, const float* __restrict__ aout,
    float* __restrict__ cagg, int E)
{
  __shared__ unsigned vt[128*64];     // 32KB: V tile bf16x2, 16B-chunk XOR swizzle
  __shared__ float einfo[128*21];     // cd[9] | radial[9] | alpha | r | c
  __shared__ float wvo[9*128];        // Wkv odd cols
  __shared__ float wc2s[512*3];
  const int tid = threadIdx.x;
  const int wid = tid >> 6, lane = tid & 63;
  const int quad = lane >> 4, colc = lane & 15;

  for (int idx = tid; idx < 9*128; idx += 256) {
    int p = idx >> 7, j = idx & 127;
    wvo[idx] = Wkv[p*KV + 2*j + 1];
  }
  for (int idx = tid; idx < 512*3; idx += 256) wc2s[idx] = Wc2[idx];

  // ---- phase 1: edge info ----
  const int e0 = blockIdx.x * 128;
  if (tid < 128) {
    int e = e0 + tid;
    float* ei = &einfo[tid*21];
    if (e < E) {
      int r = row[e], c = col[e];
      float cd[9];
      #pragma unroll
      for (int i = 0; i < 9; ++i) cd[i] = coord[(size_t)r*9+i] - coord[(size_t)c*9+i];
      #pragma unroll
      for (int i = 0; i < 9; ++i) ei[i] = cd[i];
      #pragma unroll
      for (int a = 0; a < 3; ++a)
        #pragma unroll
        for (int b = 0; b < 3; ++b)
          ei[9 + a*3+b] = cd[a*3]*cd[b*3] + cd[a*3+1]*cd[b*3+1] + cd[a*3+2]*cd[b*3+2];
      ei[18] = aout[e];             // normalized alpha
      ei[19] = __int_as_float(r);
      ei[20] = __int_as_float(c);
    } else {
      #pragma unroll
      for (int i = 0; i < 21; ++i) ei[i] = 0.f;   // alpha=0, r=c=0 -> inert
    }
  }
  __syncthreads();

  // ---- phase 2: V tile (each wave one edge per iteration) ----
  for (int i = 0; i < 32; ++i) {
    int el = i*4 + wid;
    const float* ei = &einfo[el*21];
    float rad[9];
    #pragma unroll
    for (int p = 0; p < 9; ++p) rad[p] = ei[9+p];
    int c = __float_as_int(ei[20]);
    float v0 = nld<KB>(vn, (size_t)c*H + 2*lane);
    float v1 = nld<KB>(vn, (size_t)c*H + 2*lane + 1);
    #pragma unroll
    for (int p = 0; p < 9; ++p) {
      v0 += rad[p]*wvo[p*128 + 2*lane];
      v1 += rad[p]*wvo[p*128 + 2*lane + 1];
    }
    unsigned pk = (unsigned)f2bf(v0) | ((unsigned)f2bf(v1) << 16);
    vt[el*64 + (((lane>>2) ^ (el&15))<<2) + (lane&3)] = pk;
  }
  __syncthreads();

  // ---- phase 3: MFMA GEMM per o-quarter + epilogue ----
  const int mrow = wid*32;
  for (int q = 0; q < 4; ++q) {
    f32x4 acc[2][8];
    #pragma unroll
    for (int a = 0; a < 2; ++a)
      #pragma unroll
      for (int n = 0; n < 8; ++n) acc[a][n] = (f32x4){0.f,0.f,0.f,0.f};
    #pragma unroll
    for (int kk = 0; kk < 4; ++kk) {
      FragU bfr[8];
      #pragma unroll
      for (int n = 0; n < 8; ++n)
        bfr[n].u = w1f[(((q*4+kk)*8+n)<<6) + lane];
      FragU afr[2];
      #pragma unroll
      for (int a = 0; a < 2; ++a) {
        int rrow = mrow + a*16 + colc;
        int chunk = kk*4 + quad;
        afr[a].u = *((const uint4*)&vt[rrow*64 + ((chunk ^ (rrow&15))<<2)]);
      }
      #pragma unroll
      for (int a = 0; a < 2; ++a)
        #pragma unroll
        for (int n = 0; n < 8; ++n)
          acc[a][n] = __builtin_amdgcn_mfma_f32_16x16x32_bf16(
              afr[a].s, bfr[n].s, acc[a][n], 0, 0, 0);
    }
    float wch[8][3];
    #pragma unroll
    for (int n = 0; n < 8; ++n) {
      int o = q*128 + n*16 + colc;
      wch[n][0] = wc2s[o*3+0]; wch[n][1] = wc2s[o*3+1]; wch[n][2] = wc2s[o*3+2];
    }
    float part[2][4][3];
    #pragma unroll
    for (int a=0;a<2;++a)
      #pragma unroll
      for (int g=0;g<4;++g) { part[a][g][0]=0.f; part[a][g][1]=0.f; part[a][g][2]=0.f; }
    #pragma unroll
    for (int a = 0; a < 2; ++a)
      #pragma unroll
      for (int n = 0; n < 8; ++n)
        #pragma unroll
        for (int g = 0; g < 4; ++g) {
          float s = acc[a][n][g];
          float hs = s / (1.f + __expf(-s));   // silu
          part[a][g][0] += hs*wch[n][0];
          part[a][g][1] += hs*wch[n][1];
          part[a][g][2] += hs*wch[n][2];
        }
    #pragma unroll
    for (int off = 1; off < 16; off <<= 1)
      #pragma unroll
      for (int a=0;a<2;++a)
        #pragma unroll
        for (int g=0;g<4;++g) {
          part[a][g][0] += __shfl_xor(part[a][g][0], off, 64);
          part[a][g][1] += __shfl_xor(part[a][g][1], off, 64);
          part[a][g][2] += __shfl_xor(part[a][g][2], off, 64);
        }
    if (colc < 3) {
      int ch = colc;
      #pragma unroll
      for (int a = 0; a < 2; ++a)
        #pragma unroll
        for (int g = 0; g < 4; ++g) {
          int el = mrow + a*16 + quad*4 + g;    // C-layout row
          const float* ei = &einfo[el*21];
          float al = ei[18];
          int r = __float_as_int(ei[19]);
          float gg = al * part[a][g][ch];
          float* cg = &cagg[(size_t)r*9 + ch*3];
          atomicAdd(cg+0, gg*ei[ch*3+0]);
          atomicAdd(cg+1, gg*ei[ch*3+1]);
          atomicAdd(cg+2, gg*ei[ch*3+2]);
        }
    }
  }
}

// ---------- K5: coord_out = coord + clip(cagg, +/-10) ----------
__global__ __launch_bounds__(256) void k_finalize_coord(
    const float* __restrict__ coord, const float* __restrict__ cagg,
    float* __restrict__ cout, int n)
{
  int i = blockIdx.x*256 + threadIdx.x;
  if (i < n) {
    float x = cagg[i];
    if (!(x == x)) x = 888.0f;
    else x = fminf(10.f, fmaxf(-10.f, x));
    cout[i] = coord[i] + x;
  }
}

template<bool KB>
static void run_pipeline(const float* h, const float* coord,
                         const int* row, const int* col,
                         const float* Wq, const float* bq,
                         const float* Wkv, const float* bkv,
                         const float* Wc1, const float* Wc2,
                         void* d_ws, float* out, int N, int E,
                         hipStream_t stream)
{
  const size_t es = KB ? 2 : 4;
  char* p = (char*)d_ws;
  void* kn = p;                    p += (size_t)N*H*es;
  void* vn = p;                    p += (size_t)N*H*es;
  void* qn = p;                    p += (size_t)N*H*es;
  float* cagg = (float*)p;         p += (size_t)N*9*4;
  int* counts = (int*)p;           p += (size_t)N*4;
  int* row_start = (int*)p;        p += (size_t)(N+1)*4;
  int* cursor = (int*)p;           p += (size_t)N*4;
  int* eidx = (int*)p;             p += (size_t)E*4;
  uint4* w1f = (uint4*)((((size_t)p) + 15) & ~(size_t)15);

  float* hout = out;
  float* cout = out + (size_t)N*H;
  float* aout = cout + (size_t)N*9;   // doubles as raw-alpha scratch

  k_zero<<<(N*10 + 255)/256, 256, 0, stream>>>(cagg, N*10);   // cagg + counts
  k_prep_w1<<<32, 256, 0, stream>>>(Wc1, w1f);
  k_hist<<<(E + 255)/256, 256, 0, stream>>>(row, counts, E);
  k_node_proj<KB><<<(N + 3)/4, 384, 0, stream>>>(h, Wq, bq, Wkv, bkv, qn, kn, vn, N);
  k_scan<<<1, 1024, 0, stream>>>(counts, row_start, cursor, N);
  k_scatter<<<(E + 255)/256, 256, 0, stream>>>(row, cursor, eidx, E);
  k_edge_alpha<KB><<<1024, 256, 0, stream>>>(coord, row, col, Wkv, qn, kn, aout, E);
  k_row_softmax<<<(N + 255)/256, 256, 0, stream>>>(row_start, eidx, aout, N);
  k_agg_row<KB><<<(N + 3)/4, 256, 0, stream>>>(h, coord, col, Wkv, row_start, eidx,
                                               aout, vn, hout, N);
  k_edge_mlp<KB><<<(E + 127)/128, 256, 0, stream>>>(coord, row, col, Wkv, Wc2, vn,
                                                    w1f, aout, cagg, E);
  k_finalize_coord<<<(N*9 + 255)/256, 256, 0, stream>>>(coord, cagg, cout, N*9);
}

extern "C" void kernel_launch(void* const* d_in, const int* in_sizes, int n_in,
                              void* d_out, int out_size, void* d_ws, size_t ws_size,
                              hipStream_t stream)
{
  const float* h     = (const float*)d_in[0];
  const float* coord = (const float*)d_in[1];
  const int* row = (const int*)d_in[2];
  const int* col = (const int*)d_in[3];
  const float* Wq  = (const float*)d_in[4];
  const float* bq  = (const float*)d_in[5];
  const float* Wkv = (const float*)d_in[6];
  const float* bkv = (const float*)d_in[7];
  const float* Wc1 = (const float*)d_in[8];
  const float* Wc2 = (const float*)d_in[9];
  const int N = in_sizes[0] / H;
  const int E = in_sizes[2];
  float* out = (float*)d_out;

  const size_t fixed = (size_t)N*9*4 + (size_t)N*4*3 + 4 + (size_t)E*4
                     + 8192*16 + 32;                       // cagg+sort+w1f
  const size_t need_f32 = (size_t)N*H*3*4 + fixed;          // ~81.3 MB
  const size_t need_b16 = (size_t)N*H*3*2 + fixed;          // ~42.9 MB

  if (ws_size >= need_f32) {
    run_pipeline<false>(h, coord, row, col, Wq, bq, Wkv, bkv, Wc1, Wc2,
                        d_ws, out, N, E, stream);
  } else if (ws_size >= need_b16) {
    run_pipeline<true>(h, coord, row, col, Wq, bq, Wkv, bkv, Wc1, Wc2,
                       d_ws, out, N, E, stream);
  } else {
    k_sentinel<<<(out_size + 255)/256, 256, 0, stream>>>(out, out_size);
  }
}